// Round 1
// baseline (598.936 us; speedup 1.0000x reference)
//
#include <hip/hip_runtime.h>

#define N    1024
#define BSZ  32
#define PS   480     // per-sample param stride: 169 W13 + 147 w1 + 147 w2 + 9 kA
#define HID  100

// ---------------------------------------------------------------------------
// Kernel 1: per-sample MLPs + composed 13x13 kernel (unchanged)
// ---------------------------------------------------------------------------
__global__ __launch_bounds__(256) void prep_kernel(
    const float* __restrict__ kernelA,
    const float* __restrict__ fc1_w1, const float* __restrict__ fc1_b1,
    const float* __restrict__ fc1_w2, const float* __restrict__ fc1_b2,
    const float* __restrict__ fc2_w1, const float* __restrict__ fc2_b1,
    const float* __restrict__ fc2_w2, const float* __restrict__ fc2_b2,
    float* __restrict__ params)
{
    int b = blockIdx.x, t = threadIdx.x;
    __shared__ float w[9], h1[HID], h2[HID], w1[147], w2[147];
    if (t < 9) w[t] = kernelA[b * 9 + t];
    __syncthreads();
    if (t < HID) {
        float s1 = fc1_b1[t], s2 = fc2_b1[t];
        #pragma unroll
        for (int i = 0; i < 9; ++i) {
            s1 = fmaf(w[i], fc1_w1[i * HID + t], s1);
            s2 = fmaf(w[i], fc2_w1[i * HID + t], s2);
        }
        h1[t] = fmaxf(s1, 0.f);
        h2[t] = fmaxf(s2, 0.f);
    }
    __syncthreads();
    if (t < 147) {
        float s1 = fc1_b2[t], s2 = fc2_b2[t];
        for (int i = 0; i < HID; ++i) {
            s1 = fmaf(h1[i], fc1_w2[i * 147 + t], s1);
            s2 = fmaf(h2[i], fc2_w2[i * 147 + t], s2);
        }
        w1[t] = s1;
        w2[t] = s2;
    }
    __syncthreads();
    float* P = params + b * PS;
    if (t < 169) {   // W13[ey][ex] = sum_m sum_{d1+d2=e} w1[m,d1] * w2[m,d2]
        int ey = t / 13, ex = t % 13;
        float s = 0.f;
        for (int m = 0; m < 3; ++m)
            for (int d1y = 0; d1y < 7; ++d1y) {
                int d2y = ey - d1y;
                if (d2y < 0 || d2y > 6) continue;
                for (int d1x = 0; d1x < 7; ++d1x) {
                    int d2x = ex - d1x;
                    if (d2x < 0 || d2x > 6) continue;
                    s = fmaf(w1[m * 49 + d1y * 7 + d1x],
                             w2[m * 49 + d2y * 7 + d2x], s);
                }
            }
        P[t] = s;
    }
    if (t < 147) { P[169 + t] = w1[t]; P[316 + t] = w2[t]; }
    if (t < 9)   P[463 + t] = w[t];
}

// ---------------------------------------------------------------------------
// Kernel 2: interior 13x13 composed conv.
// Restructured: LDS holds ONLY r (76x140 = 42.6 KB, 3 blocks/CU).
//   phase A: r = f - corr3x3(x,kA) computed straight from global (x via L1/L2,
//            3x8 window = 2 aligned float4 per row), quad written to LDS
//            immediately (no aliasing hazard, no register hoard).
//   ONE __syncthreads.
//   phase B: 8x4 outputs/thread (TR=64): 20-row rolling window, 4 b128/row
//            amortized over up to 8 accumulator rows -> 2.5 LDS dwords/output
//            (vs 4.0 before). Lane stride 16B -> conflict-free b128.
// Epilogue re-reads x from global (coalesced b128), L2-hot.
// ---------------------------------------------------------------------------
#define TR  64
#define TC  128
#define RRW 76     // r rows = TR + 12
#define RC  140    // r row pitch (TC + 12), 560 B rows, 16B-aligned
#define QPR 35     // float4 quads per r row
#define NQ  (RRW * QPR)   // 2660

__device__ __forceinline__ void conv_row4(const float* win, const float* __restrict__ P,
                                          int ky, float* accRow)
{
    #pragma unroll
    for (int c = 0; c < 13; ++c) {
        float tv = P[ky * 13 + c];          // block-uniform -> scalar load
        #pragma unroll
        for (int j = 0; j < 4; ++j)
            accRow[j] = fmaf(win[c + j], tv, accRow[j]);
    }
}

__global__ __launch_bounds__(256, 3) void main_kernel(
    const float* __restrict__ X, const float* __restrict__ F,
    const float* __restrict__ params, float* __restrict__ out)
{
    __shared__ __align__(16) float rbuf[RRW * RC];   // 42560 B -> 3 blocks/CU
    const int t  = threadIdx.x;
    const int b  = blockIdx.z;
    const int y0 = blockIdx.y * TR;
    const int x0 = blockIdx.x * TC;
    const float* P  = params + b * PS;
    const float* Xb = X + (size_t)b * N * N;
    const float* Fb = F + (size_t)b * N * N;
    float*       Ob = out + (size_t)b * N * N;

    float ka[9];
    #pragma unroll
    for (int i = 0; i < 9; ++i) ka[i] = P[463 + i];  // uniform -> SGPR

    // ---- phase A: r tile straight from global into LDS, quad-granular.
    // r origin = (y0-6, x0-6); quad col start gc == 2 (mod 4), so the 8-wide
    // x window [gc-2, gc+5] is two 16B-aligned float4 and f is two aligned
    // float2. All image-boundary crossings land on quad/pair boundaries
    // (x0,N multiples of 4), so in/out tests are whole-vector tests.
    for (int idx = t; idx < NQ; idx += 256) {
        int i  = idx / QPR;
        int j  = (idx - i * QPR) * 4;
        int gr = y0 - 6 + i;          // global r row
        int gc = x0 - 6 + j;          // global col of quad start
        float4 v = make_float4(0.f, 0.f, 0.f, 0.f);
        if (gr >= 0 && gr < N) {
            float w8[3][8];
            #pragma unroll
            for (int dy = 0; dy < 3; ++dy) {
                int ry = gr - 1 + dy;
                float4 qa = make_float4(0.f, 0.f, 0.f, 0.f);
                float4 qb = make_float4(0.f, 0.f, 0.f, 0.f);
                if (ry >= 0 && ry < N) {
                    const float* xr = Xb + (size_t)ry * N;
                    if (gc - 2 >= 0 && gc + 1 < N)
                        qa = *reinterpret_cast<const float4*>(xr + gc - 2);
                    if (gc + 2 >= 0 && gc + 5 < N)
                        qb = *reinterpret_cast<const float4*>(xr + gc + 2);
                }
                w8[dy][0] = qa.x; w8[dy][1] = qa.y; w8[dy][2] = qa.z; w8[dy][3] = qa.w;
                w8[dy][4] = qb.x; w8[dy][5] = qb.y; w8[dy][6] = qb.z; w8[dy][7] = qb.w;
            }
            float s[4] = {0.f, 0.f, 0.f, 0.f};
            #pragma unroll
            for (int dy = 0; dy < 3; ++dy)
                #pragma unroll
                for (int dx = 0; dx < 3; ++dx) {
                    float kv = ka[dy * 3 + dx];
                    #pragma unroll
                    for (int c = 0; c < 4; ++c)   // x col gc+c+dx-1 -> w8 idx c+dx+1
                        s[c] = fmaf(kv, w8[dy][c + dx + 1], s[c]);
                }
            const float* fr = Fb + (size_t)gr * N;
            if (gc >= 0 && gc + 1 < N) {
                float2 f0 = *reinterpret_cast<const float2*>(fr + gc);
                v.x = f0.x - s[0]; v.y = f0.y - s[1];
            }
            if (gc + 2 >= 0 && gc + 3 < N) {
                float2 f1 = *reinterpret_cast<const float2*>(fr + gc + 2);
                v.z = f1.x - s[2]; v.w = f1.y - s[3];
            }
        }
        *reinterpret_cast<float4*>(&rbuf[i * RC + j]) = v;
    }
    __syncthreads();

    // ---- phase B: 13x13 composed conv, 8 rows x 4 cols per thread
    const int tx4 = (t & 31) * 4;    // col offset 0..124 (16B lane stride)
    const int ty8 = (t >> 5) * 8;    // row offset 0..56
    const float* rb = &rbuf[ty8 * RC + tx4];

    float acc[8][4] = {{0.f,0.f,0.f,0.f},{0.f,0.f,0.f,0.f},
                       {0.f,0.f,0.f,0.f},{0.f,0.f,0.f,0.f},
                       {0.f,0.f,0.f,0.f},{0.f,0.f,0.f,0.f},
                       {0.f,0.f,0.f,0.f},{0.f,0.f,0.f,0.f}};
    float win[16];

    #define LOAD_WIN(rr)                                                      \
        { float4 v0 = *reinterpret_cast<const float4*>(rb + (rr) * RC);       \
          float4 v1 = *reinterpret_cast<const float4*>(rb + (rr) * RC + 4);   \
          float4 v2 = *reinterpret_cast<const float4*>(rb + (rr) * RC + 8);   \
          float4 v3 = *reinterpret_cast<const float4*>(rb + (rr) * RC + 12);  \
          win[0]=v0.x; win[1]=v0.y; win[2]=v0.z; win[3]=v0.w;                 \
          win[4]=v1.x; win[5]=v1.y; win[6]=v1.z; win[7]=v1.w;                 \
          win[8]=v2.x; win[9]=v2.y; win[10]=v2.z; win[11]=v2.w;               \
          win[12]=v3.x; win[13]=v3.y; win[14]=v3.z; win[15]=v3.w; }

    #pragma unroll
    for (int rr = 0; rr < 20; ++rr) {          // rolling window rows
        LOAD_WIN(rr);
        const int ilo = (rr - 12 > 0) ? rr - 12 : 0;
        const int ihi = (rr < 7) ? rr : 7;
        #pragma unroll
        for (int i = ilo; i <= ihi; ++i)
            conv_row4(win, P, rr - i, acc[i]);
    }

    // ---- epilogue: out = x + G2 (x re-read from global, coalesced b128)
    #pragma unroll
    for (int i = 0; i < 8; ++i) {
        const int gy = y0 + ty8 + i;
        const float4 xq = *reinterpret_cast<const float4*>(
            &Xb[(size_t)gy * N + x0 + tx4]);
        float4 o;
        o.x = xq.x + acc[i][0]; o.y = xq.y + acc[i][1];
        o.z = xq.z + acc[i][2]; o.w = xq.w + acc[i][3];
        *reinterpret_cast<float4*>(&Ob[(size_t)gy * N + x0 + tx4]) = o;
    }
}

// ---------------------------------------------------------------------------
// Kernel 3: exact two-stage recompute of the width-3 border band (unchanged)
// ---------------------------------------------------------------------------
#define SEG 64
#define AXX 14          // x across size
#define AXU (SEG + 14)  // x along size   78
#define ARR 12          // r across size
#define ARU (SEG + 12)  // r along size   76
#define ATA 6           // tmp across size
#define ATU (SEG + 6)   // tmp along size 70

__global__ __launch_bounds__(256) void border_kernel(
    const float* __restrict__ X, const float* __restrict__ F,
    const float* __restrict__ params, float* __restrict__ out)
{
    __shared__ float xs[AXX * AXU];
    __shared__ float rs[ARR * ARU];
    __shared__ float tmp[3 * ATA * ATU];
    __shared__ float sw1[147], sw2[147];

    const int  t    = threadIdx.x;
    const int  b    = blockIdx.y;
    const int  seg  = blockIdx.x;
    const int  edge = seg >> 4;          // 0 top, 1 bottom, 2 left, 3 right
    const int  s    = seg & 15;
    const bool vert = edge >= 2;
    const bool hi   = (edge == 1) || (edge == 3);
    const int  T0   = hi ? (N - 6) : 0;  // tmp across origin
    const int  V0   = hi ? (N - 3) : 0;  // output across origin
    const int  D    = hi ? 3 : 0;        // V0 - T0
    const int  u0   = vert ? (3 + s * SEG) : (s * SEG);
    const int  acr0x = T0 - 4, al0x = u0 - 7;
    const int  acr0r = T0 - 3, al0r = u0 - 6;

    const float* P  = params + b * PS;
    const float* Xb = X + (size_t)b * N * N;
    const float* Fb = F + (size_t)b * N * N;
    float*       Ob = out + (size_t)b * N * N;

    if (t < 147) { sw1[t] = P[169 + t]; sw2[t] = P[316 + t]; }
    float ka[9];
    #pragma unroll
    for (int i = 0; i < 9; ++i) ka[i] = P[463 + i];

    // stage x (zero-extended)
    for (int idx = t; idx < AXX * AXU; idx += 256) {
        int a = vert ? (idx % AXX) : (idx / AXU);
        int u = vert ? (idx / AXX) : (idx % AXU);
        int ga = acr0x + a, gl = al0x + u;
        int gy = vert ? gl : ga, gx = vert ? ga : gl;
        xs[a * AXU + u] =
            (gy >= 0 && gy < N && gx >= 0 && gx < N) ? Xb[gy * N + gx] : 0.f;
    }
    __syncthreads();

    // r = f - corr3x3(x,kA), zero outside image
    for (int idx = t; idx < ARR * ARU; idx += 256) {
        int a = vert ? (idx % ARR) : (idx / ARU);
        int u = vert ? (idx / ARR) : (idx % ARU);
        int ga = acr0r + a, gl = al0r + u;
        int gy = vert ? gl : ga, gx = vert ? ga : gl;
        float v = 0.f;
        if (gy >= 0 && gy < N && gx >= 0 && gx < N) {
            float sc = 0.f;
            #pragma unroll
            for (int da = 0; da < 3; ++da)
                #pragma unroll
                for (int dl = 0; dl < 3; ++dl)
                    sc = fmaf(ka[vert ? (dl * 3 + da) : (da * 3 + dl)],
                              xs[(a + da) * AXU + (u + dl)], sc);
            v = Fb[gy * N + gx] - sc;
        }
        rs[a * ARU + u] = v;
    }
    __syncthreads();

    // tmp[m, a, u]: zero if along position outside image (reference zeroing)
    for (int idx = t; idx < 3 * ATA * ATU; idx += 256) {
        int m   = idx / (ATA * ATU);
        int rem = idx - m * (ATA * ATU);
        int a = rem / ATU, u = rem % ATU;
        int gl = (u0 - 3) + u;
        float sc = 0.f;
        if (gl >= 0 && gl < N) {
            #pragma unroll
            for (int da = 0; da < 7; ++da)
                #pragma unroll
                for (int dl = 0; dl < 7; ++dl)
                    sc = fmaf(sw1[m * 49 + (vert ? (dl * 7 + da) : (da * 7 + dl))],
                              rs[(a + da) * ARU + (u + dl)], sc);
        }
        tmp[idx] = sc;
    }
    __syncthreads();

    // outputs: 3 across x SEG along
    for (int idx = t; idx < 3 * SEG; idx += 256) {
        int v = idx / SEG, u = idx - (idx / SEG) * SEG;
        int gl = u0 + u, ga = V0 + v;
        if (vert && gl >= N - 3) continue;   // partial last vertical segment
        float sc = 0.f;
        #pragma unroll
        for (int m = 0; m < 3; ++m)
            #pragma unroll
            for (int d2a = 0; d2a < 7; ++d2a) {
                int aT = v + d2a - 3 + D;    // tmp across index; OOR => ref zeroes
                if (aT < 0 || aT >= ATA) continue;
                #pragma unroll
                for (int d2l = 0; d2l < 7; ++d2l)
                    sc = fmaf(sw2[m * 49 + (vert ? (d2l * 7 + d2a) : (d2a * 7 + d2l))],
                              tmp[(m * ATA + aT) * ATU + (u + d2l)], sc);
            }
        int gy = vert ? gl : ga, gx = vert ? ga : gl;
        float xv = xs[(ga - acr0x) * AXU + (gl - al0x)];
        Ob[gy * N + gx] = xv + sc;
    }
}

// ---------------------------------------------------------------------------
extern "C" void kernel_launch(void* const* d_in, const int* in_sizes, int n_in,
                              void* d_out, int out_size, void* d_ws, size_t ws_size,
                              hipStream_t stream)
{
    const float* x    = (const float*)d_in[0];
    const float* f    = (const float*)d_in[1];
    const float* kA   = (const float*)d_in[2];
    const float* f1w1 = (const float*)d_in[3];
    const float* f1b1 = (const float*)d_in[4];
    const float* f1w2 = (const float*)d_in[5];
    const float* f1b2 = (const float*)d_in[6];
    const float* f2w1 = (const float*)d_in[7];
    const float* f2b1 = (const float*)d_in[8];
    const float* f2w2 = (const float*)d_in[9];
    const float* f2b2 = (const float*)d_in[10];
    float* out    = (float*)d_out;
    float* params = (float*)d_ws;   // BSZ * PS floats = 61440 B

    prep_kernel<<<BSZ, 256, 0, stream>>>(kA, f1w1, f1b1, f1w2, f1b2,
                                         f2w1, f2b1, f2w2, f2b2, params);
    main_kernel<<<dim3(N / TC, N / TR, BSZ), 256, 0, stream>>>(x, f, params, out);
    border_kernel<<<dim3(64, BSZ), 256, 0, stream>>>(x, f, params, out);
}

// Round 2
// 510.062 us; speedup vs baseline: 1.1742x; 1.1742x over previous
//
#include <hip/hip_runtime.h>

#define N    1024
#define BSZ  32
#define PS   480     // per-sample param stride: 169 W13 + 147 w1 + 147 w2 + 9 kA
#define HID  100

// ---------------------------------------------------------------------------
// Kernel 1: per-sample MLPs + composed 13x13 kernel (unchanged)
// ---------------------------------------------------------------------------
__global__ __launch_bounds__(256) void prep_kernel(
    const float* __restrict__ kernelA,
    const float* __restrict__ fc1_w1, const float* __restrict__ fc1_b1,
    const float* __restrict__ fc1_w2, const float* __restrict__ fc1_b2,
    const float* __restrict__ fc2_w1, const float* __restrict__ fc2_b1,
    const float* __restrict__ fc2_w2, const float* __restrict__ fc2_b2,
    float* __restrict__ params)
{
    int b = blockIdx.x, t = threadIdx.x;
    __shared__ float w[9], h1[HID], h2[HID], w1[147], w2[147];
    if (t < 9) w[t] = kernelA[b * 9 + t];
    __syncthreads();
    if (t < HID) {
        float s1 = fc1_b1[t], s2 = fc2_b1[t];
        #pragma unroll
        for (int i = 0; i < 9; ++i) {
            s1 = fmaf(w[i], fc1_w1[i * HID + t], s1);
            s2 = fmaf(w[i], fc2_w1[i * HID + t], s2);
        }
        h1[t] = fmaxf(s1, 0.f);
        h2[t] = fmaxf(s2, 0.f);
    }
    __syncthreads();
    if (t < 147) {
        float s1 = fc1_b2[t], s2 = fc2_b2[t];
        for (int i = 0; i < HID; ++i) {
            s1 = fmaf(h1[i], fc1_w2[i * 147 + t], s1);
            s2 = fmaf(h2[i], fc2_w2[i * 147 + t], s2);
        }
        w1[t] = s1;
        w2[t] = s2;
    }
    __syncthreads();
    float* P = params + b * PS;
    if (t < 169) {   // W13[ey][ex] = sum_m sum_{d1+d2=e} w1[m,d1] * w2[m,d2]
        int ey = t / 13, ex = t % 13;
        float s = 0.f;
        for (int m = 0; m < 3; ++m)
            for (int d1y = 0; d1y < 7; ++d1y) {
                int d2y = ey - d1y;
                if (d2y < 0 || d2y > 6) continue;
                for (int d1x = 0; d1x < 7; ++d1x) {
                    int d2x = ex - d1x;
                    if (d2x < 0 || d2x > 6) continue;
                    s = fmaf(w1[m * 49 + d1y * 7 + d1x],
                             w2[m * 49 + d2y * 7 + d2x], s);
                }
            }
        P[t] = s;
    }
    if (t < 147) { P[169 + t] = w1[t]; P[316 + t] = w2[t]; }
    if (t < 9)   P[463 + t] = w[t];
}

// ---------------------------------------------------------------------------
// Kernel 2: interior 13x13 composed conv.
// LDS holds ONLY r (44x140 = 24.6 KB -> 6 blocks/CU, __launch_bounds__(256,6)).
//   phase A: r = f - corr3x3(x,kA) straight from global, quad written to LDS.
//   ONE __syncthreads.
//   phase B: 4x4 outputs/thread, THREE tap-row passes (ky 0-4 / 5-9 / 10-12).
//     Each pass hoists its <=65 taps into named scalars (one s_load burst,
//     one lgkmcnt drain), then the inner loop is PURE DS + FMA: since SMEM
//     and DS share lgkmcnt but complete out of order, any in-loop s_load
//     forces lgkmcnt(0) and drains the ds_read pipeline -- segregating them
//     lets counted lgkmcnt waits keep the window prefetch in flight.
//     Explicit winA/winB double buffer: prefetch row rr+1 before computing rr.
// ---------------------------------------------------------------------------
#define TR  32
#define TC  128
#define RRW 44     // r rows = TR + 12
#define RC  140    // r row pitch (TC + 12), 560 B rows, 16B-aligned
#define QPR 35     // float4 quads per r row
#define NQ  (RRW * QPR)   // 1540

// declare one 13-tap kernel row as named scalars (uniform -> SGPRs)
#define DECL_ROW(R, base)                                                     \
    const float R##_0 = P[(base)],      R##_1 = P[(base) + 1],                \
                R##_2 = P[(base) + 2],  R##_3 = P[(base) + 3],                \
                R##_4 = P[(base) + 4],  R##_5 = P[(base) + 5],                \
                R##_6 = P[(base) + 6],  R##_7 = P[(base) + 7],                \
                R##_8 = P[(base) + 8],  R##_9 = P[(base) + 9],                \
                R##_10 = P[(base) + 10], R##_11 = P[(base) + 11],             \
                R##_12 = P[(base) + 12];

#define CRC(w, R, a, c)                                                       \
    (a)[0] = fmaf((w)[(c) + 0], R##_##c, (a)[0]);                             \
    (a)[1] = fmaf((w)[(c) + 1], R##_##c, (a)[1]);                             \
    (a)[2] = fmaf((w)[(c) + 2], R##_##c, (a)[2]);                             \
    (a)[3] = fmaf((w)[(c) + 3], R##_##c, (a)[3]);

// one 13-tap conv row applied to a 4-wide window slice
#define CR4(w, R, a) do {                                                     \
    CRC(w, R, a, 0)  CRC(w, R, a, 1)  CRC(w, R, a, 2)  CRC(w, R, a, 3)        \
    CRC(w, R, a, 4)  CRC(w, R, a, 5)  CRC(w, R, a, 6)  CRC(w, R, a, 7)        \
    CRC(w, R, a, 8)  CRC(w, R, a, 9)  CRC(w, R, a, 10) CRC(w, R, a, 11)       \
    CRC(w, R, a, 12) } while (0)

#define LW(wn, rr) {                                                          \
    float4 v0 = *reinterpret_cast<const float4*>(rb + (rr) * RC);             \
    float4 v1 = *reinterpret_cast<const float4*>(rb + (rr) * RC + 4);         \
    float4 v2 = *reinterpret_cast<const float4*>(rb + (rr) * RC + 8);         \
    float4 v3 = *reinterpret_cast<const float4*>(rb + (rr) * RC + 12);        \
    wn[0] = v0.x; wn[1] = v0.y; wn[2]  = v0.z; wn[3]  = v0.w;                 \
    wn[4] = v1.x; wn[5] = v1.y; wn[6]  = v1.z; wn[7]  = v1.w;                 \
    wn[8] = v2.x; wn[9] = v2.y; wn[10] = v2.z; wn[11] = v2.w;                 \
    wn[12] = v3.x; wn[13] = v3.y; wn[14] = v3.z; wn[15] = v3.w; }

__global__ __launch_bounds__(256, 6) void main_kernel(
    const float* __restrict__ X, const float* __restrict__ F,
    const float* __restrict__ params, float* __restrict__ out)
{
    __shared__ __align__(16) float rbuf[RRW * RC];   // 24640 B -> 6 blocks/CU
    const int t  = threadIdx.x;
    const int b  = blockIdx.z;
    const int y0 = blockIdx.y * TR;
    const int x0 = blockIdx.x * TC;
    const float* P  = params + b * PS;
    const float* Xb = X + (size_t)b * N * N;
    const float* Fb = F + (size_t)b * N * N;
    float*       Ob = out + (size_t)b * N * N;

    float ka[9];
    #pragma unroll
    for (int i = 0; i < 9; ++i) ka[i] = P[463 + i];  // uniform -> SGPR

    // ---- phase A: r tile straight from global into LDS, quad-granular.
    // r origin = (y0-6, x0-6); quad col start gc == 2 (mod 4), so the 8-wide
    // x window [gc-2, gc+5] is two 16B-aligned float4 and f is two aligned
    // float2. Boundary crossings land on vector boundaries.
    for (int idx = t; idx < NQ; idx += 256) {
        int i  = idx / QPR;
        int j  = (idx - i * QPR) * 4;
        int gr = y0 - 6 + i;          // global r row
        int gc = x0 - 6 + j;          // global col of quad start
        float4 v = make_float4(0.f, 0.f, 0.f, 0.f);
        if (gr >= 0 && gr < N) {
            float w8[3][8];
            #pragma unroll
            for (int dy = 0; dy < 3; ++dy) {
                int ry = gr - 1 + dy;
                float4 qa = make_float4(0.f, 0.f, 0.f, 0.f);
                float4 qb = make_float4(0.f, 0.f, 0.f, 0.f);
                if (ry >= 0 && ry < N) {
                    const float* xr = Xb + (size_t)ry * N;
                    if (gc - 2 >= 0 && gc + 1 < N)
                        qa = *reinterpret_cast<const float4*>(xr + gc - 2);
                    if (gc + 2 >= 0 && gc + 5 < N)
                        qb = *reinterpret_cast<const float4*>(xr + gc + 2);
                }
                w8[dy][0] = qa.x; w8[dy][1] = qa.y; w8[dy][2] = qa.z; w8[dy][3] = qa.w;
                w8[dy][4] = qb.x; w8[dy][5] = qb.y; w8[dy][6] = qb.z; w8[dy][7] = qb.w;
            }
            float s[4] = {0.f, 0.f, 0.f, 0.f};
            #pragma unroll
            for (int dy = 0; dy < 3; ++dy)
                #pragma unroll
                for (int dx = 0; dx < 3; ++dx) {
                    float kv = ka[dy * 3 + dx];
                    #pragma unroll
                    for (int c = 0; c < 4; ++c)
                        s[c] = fmaf(kv, w8[dy][c + dx + 1], s[c]);
                }
            const float* fr = Fb + (size_t)gr * N;
            if (gc >= 0 && gc + 1 < N) {
                float2 f0 = *reinterpret_cast<const float2*>(fr + gc);
                v.x = f0.x - s[0]; v.y = f0.y - s[1];
            }
            if (gc + 2 >= 0 && gc + 3 < N) {
                float2 f1 = *reinterpret_cast<const float2*>(fr + gc + 2);
                v.z = f1.x - s[2]; v.w = f1.y - s[3];
            }
        }
        *reinterpret_cast<float4*>(&rbuf[i * RC + j]) = v;
    }
    __syncthreads();

    // ---- phase B: 13x13 composed conv, 4 rows x 4 cols per thread,
    // three SMEM-segregated tap passes with double-buffered window prefetch.
    const int tx4 = (t & 31) * 4;    // col offset 0..124 (16B lane stride)
    const int ty4 = (t >> 5) * 4;    // row offset 0..28
    const float* rb = &rbuf[ty4 * RC + tx4];

    float acc[4][4] = {{0.f,0.f,0.f,0.f},{0.f,0.f,0.f,0.f},
                       {0.f,0.f,0.f,0.f},{0.f,0.f,0.f,0.f}};
    float winA[16], winB[16];

    // ---- pass 0: tap rows ky 0..4, window rows rr 0..7
    {
        DECL_ROW(K0, 0)  DECL_ROW(K1, 13) DECL_ROW(K2, 26)
        DECL_ROW(K3, 39) DECL_ROW(K4, 52)
        LW(winA, 0) LW(winB, 1)
        CR4(winA, K0, acc[0]);
        LW(winA, 2)
        CR4(winB, K1, acc[0]); CR4(winB, K0, acc[1]);
        LW(winB, 3)
        CR4(winA, K2, acc[0]); CR4(winA, K1, acc[1]); CR4(winA, K0, acc[2]);
        LW(winA, 4)
        CR4(winB, K3, acc[0]); CR4(winB, K2, acc[1]); CR4(winB, K1, acc[2]);
        CR4(winB, K0, acc[3]);
        LW(winB, 5)
        CR4(winA, K4, acc[0]); CR4(winA, K3, acc[1]); CR4(winA, K2, acc[2]);
        CR4(winA, K1, acc[3]);
        LW(winA, 6)
        CR4(winB, K4, acc[1]); CR4(winB, K3, acc[2]); CR4(winB, K2, acc[3]);
        LW(winB, 7)
        CR4(winA, K4, acc[2]); CR4(winA, K3, acc[3]);
        CR4(winB, K4, acc[3]);
    }
    // ---- pass 1: tap rows ky 5..9, window rows rr 5..12
    {
        DECL_ROW(K0, 65)  DECL_ROW(K1, 78) DECL_ROW(K2, 91)
        DECL_ROW(K3, 104) DECL_ROW(K4, 117)
        LW(winA, 5) LW(winB, 6)
        CR4(winA, K0, acc[0]);
        LW(winA, 7)
        CR4(winB, K1, acc[0]); CR4(winB, K0, acc[1]);
        LW(winB, 8)
        CR4(winA, K2, acc[0]); CR4(winA, K1, acc[1]); CR4(winA, K0, acc[2]);
        LW(winA, 9)
        CR4(winB, K3, acc[0]); CR4(winB, K2, acc[1]); CR4(winB, K1, acc[2]);
        CR4(winB, K0, acc[3]);
        LW(winB, 10)
        CR4(winA, K4, acc[0]); CR4(winA, K3, acc[1]); CR4(winA, K2, acc[2]);
        CR4(winA, K1, acc[3]);
        LW(winA, 11)
        CR4(winB, K4, acc[1]); CR4(winB, K3, acc[2]); CR4(winB, K2, acc[3]);
        LW(winB, 12)
        CR4(winA, K4, acc[2]); CR4(winA, K3, acc[3]);
        CR4(winB, K4, acc[3]);
    }
    // ---- pass 2: tap rows ky 10..12, window rows rr 10..15
    {
        DECL_ROW(K0, 130) DECL_ROW(K1, 143) DECL_ROW(K2, 156)
        LW(winA, 10) LW(winB, 11)
        CR4(winA, K0, acc[0]);
        LW(winA, 12)
        CR4(winB, K1, acc[0]); CR4(winB, K0, acc[1]);
        LW(winB, 13)
        CR4(winA, K2, acc[0]); CR4(winA, K1, acc[1]); CR4(winA, K0, acc[2]);
        LW(winA, 14)
        CR4(winB, K2, acc[1]); CR4(winB, K1, acc[2]); CR4(winB, K0, acc[3]);
        LW(winB, 15)
        CR4(winA, K2, acc[2]); CR4(winA, K1, acc[3]);
        CR4(winB, K2, acc[3]);
    }

    // ---- epilogue: out = x + G2 (x re-read from global, coalesced b128)
    #pragma unroll
    for (int i = 0; i < 4; ++i) {
        const int gy = y0 + ty4 + i;
        const float4 xq = *reinterpret_cast<const float4*>(
            &Xb[(size_t)gy * N + x0 + tx4]);
        float4 o;
        o.x = xq.x + acc[i][0]; o.y = xq.y + acc[i][1];
        o.z = xq.z + acc[i][2]; o.w = xq.w + acc[i][3];
        *reinterpret_cast<float4*>(&Ob[(size_t)gy * N + x0 + tx4]) = o;
    }
}

// ---------------------------------------------------------------------------
// Kernel 3: exact two-stage recompute of the width-3 border band (unchanged)
// ---------------------------------------------------------------------------
#define SEG 64
#define AXX 14          // x across size
#define AXU (SEG + 14)  // x along size   78
#define ARR 12          // r across size
#define ARU (SEG + 12)  // r along size   76
#define ATA 6           // tmp across size
#define ATU (SEG + 6)   // tmp along size 70

__global__ __launch_bounds__(256) void border_kernel(
    const float* __restrict__ X, const float* __restrict__ F,
    const float* __restrict__ params, float* __restrict__ out)
{
    __shared__ float xs[AXX * AXU];
    __shared__ float rs[ARR * ARU];
    __shared__ float tmp[3 * ATA * ATU];
    __shared__ float sw1[147], sw2[147];

    const int  t    = threadIdx.x;
    const int  b    = blockIdx.y;
    const int  seg  = blockIdx.x;
    const int  edge = seg >> 4;          // 0 top, 1 bottom, 2 left, 3 right
    const int  s    = seg & 15;
    const bool vert = edge >= 2;
    const bool hi   = (edge == 1) || (edge == 3);
    const int  T0   = hi ? (N - 6) : 0;  // tmp across origin
    const int  V0   = hi ? (N - 3) : 0;  // output across origin
    const int  D    = hi ? 3 : 0;        // V0 - T0
    const int  u0   = vert ? (3 + s * SEG) : (s * SEG);
    const int  acr0x = T0 - 4, al0x = u0 - 7;
    const int  acr0r = T0 - 3, al0r = u0 - 6;

    const float* P  = params + b * PS;
    const float* Xb = X + (size_t)b * N * N;
    const float* Fb = F + (size_t)b * N * N;
    float*       Ob = out + (size_t)b * N * N;

    if (t < 147) { sw1[t] = P[169 + t]; sw2[t] = P[316 + t]; }
    float ka[9];
    #pragma unroll
    for (int i = 0; i < 9; ++i) ka[i] = P[463 + i];

    // stage x (zero-extended)
    for (int idx = t; idx < AXX * AXU; idx += 256) {
        int a = vert ? (idx % AXX) : (idx / AXU);
        int u = vert ? (idx / AXX) : (idx % AXU);
        int ga = acr0x + a, gl = al0x + u;
        int gy = vert ? gl : ga, gx = vert ? ga : gl;
        xs[a * AXU + u] =
            (gy >= 0 && gy < N && gx >= 0 && gx < N) ? Xb[gy * N + gx] : 0.f;
    }
    __syncthreads();

    // r = f - corr3x3(x,kA), zero outside image
    for (int idx = t; idx < ARR * ARU; idx += 256) {
        int a = vert ? (idx % ARR) : (idx / ARU);
        int u = vert ? (idx / ARR) : (idx % ARU);
        int ga = acr0r + a, gl = al0r + u;
        int gy = vert ? gl : ga, gx = vert ? ga : gl;
        float v = 0.f;
        if (gy >= 0 && gy < N && gx >= 0 && gx < N) {
            float sc = 0.f;
            #pragma unroll
            for (int da = 0; da < 3; ++da)
                #pragma unroll
                for (int dl = 0; dl < 3; ++dl)
                    sc = fmaf(ka[vert ? (dl * 3 + da) : (da * 3 + dl)],
                              xs[(a + da) * AXU + (u + dl)], sc);
            v = Fb[gy * N + gx] - sc;
        }
        rs[a * ARU + u] = v;
    }
    __syncthreads();

    // tmp[m, a, u]: zero if along position outside image (reference zeroing)
    for (int idx = t; idx < 3 * ATA * ATU; idx += 256) {
        int m   = idx / (ATA * ATU);
        int rem = idx - m * (ATA * ATU);
        int a = rem / ATU, u = rem % ATU;
        int gl = (u0 - 3) + u;
        float sc = 0.f;
        if (gl >= 0 && gl < N) {
            #pragma unroll
            for (int da = 0; da < 7; ++da)
                #pragma unroll
                for (int dl = 0; dl < 7; ++dl)
                    sc = fmaf(sw1[m * 49 + (vert ? (dl * 7 + da) : (da * 7 + dl))],
                              rs[(a + da) * ARU + (u + dl)], sc);
        }
        tmp[idx] = sc;
    }
    __syncthreads();

    // outputs: 3 across x SEG along
    for (int idx = t; idx < 3 * SEG; idx += 256) {
        int v = idx / SEG, u = idx - (idx / SEG) * SEG;
        int gl = u0 + u, ga = V0 + v;
        if (vert && gl >= N - 3) continue;   // partial last vertical segment
        float sc = 0.f;
        #pragma unroll
        for (int m = 0; m < 3; ++m)
            #pragma unroll
            for (int d2a = 0; d2a < 7; ++d2a) {
                int aT = v + d2a - 3 + D;    // tmp across index; OOR => ref zeroes
                if (aT < 0 || aT >= ATA) continue;
                #pragma unroll
                for (int d2l = 0; d2l < 7; ++d2l)
                    sc = fmaf(sw2[m * 49 + (vert ? (d2l * 7 + d2a) : (d2a * 7 + d2l))],
                              tmp[(m * ATA + aT) * ATU + (u + d2l)], sc);
            }
        int gy = vert ? gl : ga, gx = vert ? ga : gl;
        float xv = xs[(ga - acr0x) * AXU + (gl - al0x)];
        Ob[gy * N + gx] = xv + sc;
    }
}

// ---------------------------------------------------------------------------
extern "C" void kernel_launch(void* const* d_in, const int* in_sizes, int n_in,
                              void* d_out, int out_size, void* d_ws, size_t ws_size,
                              hipStream_t stream)
{
    const float* x    = (const float*)d_in[0];
    const float* f    = (const float*)d_in[1];
    const float* kA   = (const float*)d_in[2];
    const float* f1w1 = (const float*)d_in[3];
    const float* f1b1 = (const float*)d_in[4];
    const float* f1w2 = (const float*)d_in[5];
    const float* f1b2 = (const float*)d_in[6];
    const float* f2w1 = (const float*)d_in[7];
    const float* f2b1 = (const float*)d_in[8];
    const float* f2w2 = (const float*)d_in[9];
    const float* f2b2 = (const float*)d_in[10];
    float* out    = (float*)d_out;
    float* params = (float*)d_ws;   // BSZ * PS floats = 61440 B

    prep_kernel<<<BSZ, 256, 0, stream>>>(kA, f1w1, f1b1, f1w2, f1b2,
                                         f2w1, f2b1, f2w2, f2b2, params);
    main_kernel<<<dim3(N / TC, N / TR, BSZ), 256, 0, stream>>>(x, f, params, out);
    border_kernel<<<dim3(64, BSZ), 256, 0, stream>>>(x, f, params, out);
}